// Round 1
// baseline (1363.541 us; speedup 1.0000x reference)
//
#include <hip/hip_runtime.h>

typedef unsigned short u16;
typedef __bf16 bf16x8 __attribute__((ext_vector_type(8)));
typedef float f32x4 __attribute__((ext_vector_type(4)));
typedef u16 u16x4 __attribute__((ext_vector_type(4)));

#define SEQ 2048
#define NQKV 6144
#define HID 4096

__device__ inline u16 f2bf(float f) {
  union { float f; unsigned u; } x; x.f = f;
  unsigned r = x.u + 0x7fffu + ((x.u >> 16) & 1u);  // RNE
  return (u16)(r >> 16);
}
__device__ inline float bf2f(u16 u) {
  union { unsigned u; float f; } x; x.u = ((unsigned)u) << 16;
  return x.f;
}
__device__ inline f32x4 mfma16(bf16x8 a, bf16x8 b, f32x4 c) {
  return __builtin_amdgcn_mfma_f32_16x16x32_bf16(a, b, c, 0, 0, 0);
}
__device__ inline void gload16(const void* g, void* l) {
  __builtin_amdgcn_global_load_lds((const __attribute__((address_space(1))) void*)g,
                                   (__attribute__((address_space(3))) void*)l,
                                   16, 0, 0);
}

// ---------- fp32 -> bf16 contiguous convert ----------
__global__ __launch_bounds__(256) void conv_kernel(const float* __restrict__ in,
                                                   u16* __restrict__ out) {
  int i = (blockIdx.x * 256 + threadIdx.x) * 4;
  float4 v = *(const float4*)(in + i);
  u16x4 o;
  o[0] = f2bf(v.x); o[1] = f2bf(v.y); o[2] = f2bf(v.z); o[3] = f2bf(v.w);
  *(u16x4*)(out + i) = o;
}

// ---------- fp32 [R][C] -> bf16 [C][R] transpose-convert ----------
__global__ __launch_bounds__(256) void transconv_kernel(const float* __restrict__ in,
                                                        u16* __restrict__ out,
                                                        int R, int C) {
  __shared__ u16 tile[32][33];
  int c0 = blockIdx.x * 32, r0 = blockIdx.y * 32;
  int tx = threadIdx.x & 31, ty = threadIdx.x >> 5;
  for (int i = 0; i < 4; ++i)
    tile[ty + 8 * i][tx] = f2bf(in[(size_t)(r0 + ty + 8 * i) * C + c0 + tx]);
  __syncthreads();
  for (int i = 0; i < 4; ++i)
    out[(size_t)(c0 + ty + 8 * i) * R + r0 + tx] = tile[tx][ty + 8 * i];
}

// ---------- bf16 GEMM: A[M][K] x Bt[N][K] -> C[M][N]  (m97 structure) ----------
__device__ inline void store_out(u16* p, float v) { *p = f2bf(v); }
__device__ inline void store_out(float* p, float v) { *p = v; }

template <typename OutT>
__global__ __launch_bounds__(256) void gemm_kernel(const u16* __restrict__ A,
                                                   const u16* __restrict__ Bt,
                                                   OutT* __restrict__ C,
                                                   int M, int N, int K) {
  __shared__ __align__(16) u16 As[128 * 32];
  __shared__ __align__(16) u16 Bs[128 * 32];
  int row0 = blockIdx.y * 128, col0 = blockIdx.x * 128;
  int t = threadIdx.x, w = t >> 6, l = t & 63;
  int wm = w >> 1, wn = w & 1;        // 2x2 waves -> 64x64 each
  int lo = l & 15, hi = l >> 4;
  f32x4 acc[4][4] = {};
  for (int kt = 0; kt < K; kt += 32) {
    for (int c = 0; c < 2; ++c) {
      int ch = w * 2 + c;             // 8 x 1KB chunks each for As/Bs
      gload16(A + (size_t)(row0 + ch * 16 + (l >> 2)) * K + kt + (l & 3) * 8, &As[ch * 512]);
      gload16(Bt + (size_t)(col0 + ch * 16 + (l >> 2)) * K + kt + (l & 3) * 8, &Bs[ch * 512]);
    }
    __syncthreads();
    bf16x8 af[4], bfr[4];
    for (int m = 0; m < 4; ++m)
      af[m] = *(const bf16x8*)&As[(wm * 64 + m * 16 + lo) * 32 + hi * 8];
    for (int n = 0; n < 4; ++n)
      bfr[n] = *(const bf16x8*)&Bs[(wn * 64 + n * 16 + lo) * 32 + hi * 8];
    for (int m = 0; m < 4; ++m)
      for (int n = 0; n < 4; ++n)
        acc[m][n] = mfma16(af[m], bfr[n], acc[m][n]);
    __syncthreads();
  }
  for (int m = 0; m < 4; ++m)
    for (int n = 0; n < 4; ++n)
      for (int r = 0; r < 4; ++r) {
        int row = row0 + wm * 64 + m * 16 + hi * 4 + r;  // C/D: row=(l>>4)*4+r
        int col = col0 + wn * 64 + n * 16 + lo;          //      col=l&15
        store_out(&C[(size_t)row * N + col], acc[m][n][r]);
      }
}

// ---------- RoPE in place on q,k regions of qkv ----------
__global__ __launch_bounds__(256) void rope_kernel(u16* __restrict__ qkv,
                                                   const float* __restrict__ cosb,
                                                   const float* __restrict__ sinb) {
  int idx = blockIdx.x * 256 + threadIdx.x;   // (m, head<40, d<64)
  int d = idx & 63;
  int head = (idx >> 6) % 40;
  int m = idx / (64 * 40);
  int s = m & (SEQ - 1);
  int col = head < 32 ? head * 128 : 4096 + (head - 32) * 128;
  u16* p = qkv + (size_t)m * NQKV + col;
  float x1 = bf2f(p[d]), x2 = bf2f(p[d + 64]);
  float c = cosb[s * 64 + d], sn = sinb[s * 64 + d];
  p[d] = f2bf(x1 * c - x2 * sn);
  p[d + 64] = f2bf(x2 * c + x1 * sn);
}

// ---------- V transpose: qkv v-region -> Vt[b][kvh][d][S] ----------
__global__ __launch_bounds__(256) void vtrans_kernel(const u16* __restrict__ qkv,
                                                     u16* __restrict__ Vt) {
  __shared__ u16 tile[32][33];
  int bid = blockIdx.x;
  int dt = bid & 3;
  int st = (bid >> 2) & 63;
  int bk = bid >> 8;               // b*8+kvh
  int b = bk >> 3, kvh = bk & 7;
  int tx = threadIdx.x & 31, ty = threadIdx.x >> 5;
  for (int i = 0; i < 4; ++i) {
    int s = st * 32 + ty + 8 * i;
    tile[ty + 8 * i][tx] = qkv[(size_t)(b * SEQ + s) * NQKV + 5120 + kvh * 128 + dt * 32 + tx];
  }
  __syncthreads();
  for (int i = 0; i < 4; ++i) {
    int d = dt * 32 + ty + 8 * i;
    Vt[((size_t)bk * 128 + d) * SEQ + st * 32 + tx] = tile[tx][ty + 8 * i];
  }
}

// ---------- flash attention: 4 waves/block, 32 q-rows/wave, KBLK=64 ----------
__global__ __launch_bounds__(256) void flash_kernel(const u16* __restrict__ qkv,
                                                    const u16* __restrict__ Vt,
                                                    u16* __restrict__ attn) {
  const float scale = 0.08838834764831843f;  // 1/sqrt(128)
  int bid = blockIdx.x;
  int qc = bid & 15;
  int h = (bid >> 4) & 31;
  int b = bid >> 9;
  int w = threadIdx.x >> 6, l = threadIdx.x & 63;
  int lo = l & 15, hi = l >> 4;
  int q0 = qc * 128 + w * 32;
  int kvh = h >> 2;

  __shared__ __align__(16) u16 P_lds[4][32][72];  // per-wave P, padded rows
  u16(*P)[72] = P_lds[w];

  bf16x8 aq[2][4];
  for (int s2 = 0; s2 < 2; ++s2) {
    const u16* qr = qkv + (size_t)(b * SEQ + q0 + s2 * 16 + lo) * NQKV + h * 128 + hi * 8;
    for (int dk = 0; dk < 4; ++dk) aq[s2][dk] = *(const bf16x8*)(qr + dk * 32);
  }
  f32x4 o[2][8] = {};
  float mreg[2][4], lreg[2][4];
  for (int s2 = 0; s2 < 2; ++s2)
    for (int r = 0; r < 4; ++r) { mreg[s2][r] = -1e30f; lreg[s2][r] = 0.f; }

  const u16* vtb = Vt + (size_t)(b * 8 + kvh) * 128 * SEQ;
  int ktmax = q0 >> 6;
  for (int kt = 0; kt <= ktmax; ++kt) {
    // ---- scores: S = Q K^T ----
    f32x4 sc[2][4];
    for (int ct = 0; ct < 4; ++ct) {
      bf16x8 kf[4];
      const u16* kr = qkv + (size_t)(b * SEQ + kt * 64 + ct * 16 + lo) * NQKV + 4096 + kvh * 128 + hi * 8;
      for (int dk = 0; dk < 4; ++dk) kf[dk] = *(const bf16x8*)(kr + dk * 32);
      for (int s2 = 0; s2 < 2; ++s2) {
        f32x4 a = {0.f, 0.f, 0.f, 0.f};
        for (int dk = 0; dk < 4; ++dk) a = mfma16(aq[s2][dk], kf[dk], a);
        sc[s2][ct] = a;
      }
    }
    bool masked = (kt == ktmax);
    // ---- online softmax ----
    for (int s2 = 0; s2 < 2; ++s2) {
      float pv[4][4];
      float tm[4] = {-1e30f, -1e30f, -1e30f, -1e30f};
      for (int ct = 0; ct < 4; ++ct)
        for (int r = 0; r < 4; ++r) {
          float v = sc[s2][ct][r] * scale;
          if (masked && (kt * 64 + ct * 16 + lo > q0 + s2 * 16 + hi * 4 + r)) v = -1e30f;
          pv[ct][r] = v;
          tm[r] = fmaxf(tm[r], v);
        }
      for (int r = 0; r < 4; ++r) {
        float t = tm[r];
        t = fmaxf(t, __shfl_xor(t, 1));
        t = fmaxf(t, __shfl_xor(t, 2));
        t = fmaxf(t, __shfl_xor(t, 4));
        t = fmaxf(t, __shfl_xor(t, 8));
        float mnew = fmaxf(mreg[s2][r], t);
        float alpha = __expf(mreg[s2][r] - mnew);
        mreg[s2][r] = mnew;
        float rs = 0.f;
        for (int ct = 0; ct < 4; ++ct) {
          float p = __expf(pv[ct][r] - mnew);
          pv[ct][r] = p;
          rs += p;
        }
        rs += __shfl_xor(rs, 1);
        rs += __shfl_xor(rs, 2);
        rs += __shfl_xor(rs, 4);
        rs += __shfl_xor(rs, 8);
        lreg[s2][r] = lreg[s2][r] * alpha + rs;
        for (int dt = 0; dt < 8; ++dt) o[s2][dt][r] *= alpha;
        for (int ct = 0; ct < 4; ++ct)
          P[s2 * 16 + hi * 4 + r][ct * 16 + lo] = f2bf(pv[ct][r]);
      }
    }
    asm volatile("s_waitcnt lgkmcnt(0)" ::: "memory");  // P writes visible before reads
    // ---- O += P V ----
    for (int kk = 0; kk < 2; ++kk) {
      bf16x8 ap[2];
      for (int s2 = 0; s2 < 2; ++s2)
        ap[s2] = *(const bf16x8*)&P[s2 * 16 + lo][kk * 32 + hi * 8];
      for (int dt = 0; dt < 8; ++dt) {
        bf16x8 vf = *(const bf16x8*)(vtb + (size_t)(dt * 16 + lo) * SEQ + kt * 64 + kk * 32 + hi * 8);
        for (int s2 = 0; s2 < 2; ++s2) o[s2][dt] = mfma16(ap[s2], vf, o[s2][dt]);
      }
    }
  }
  // ---- epilogue ----
  for (int s2 = 0; s2 < 2; ++s2)
    for (int dt = 0; dt < 8; ++dt)
      for (int r = 0; r < 4; ++r) {
        float v2 = o[s2][dt][r] / lreg[s2][r];
        attn[(size_t)(b * SEQ + q0 + s2 * 16 + hi * 4 + r) * 4096 + h * 128 + dt * 16 + lo] = f2bf(v2);
      }
}

extern "C" void kernel_launch(void* const* d_in, const int* in_sizes, int n_in,
                              void* d_out, int out_size, void* d_ws, size_t ws_size,
                              hipStream_t stream) {
  const float* hidden = (const float*)d_in[0];
  const float* Wqkv = (const float*)d_in[1];
  const float* Wo = (const float*)d_in[2];
  const float* cosb = (const float*)d_in[3];
  const float* sinb = (const float*)d_in[4];
  // d_in[5] (attention_mask) is exactly causal triu(-1e9): applied analytically.
  float* out = (float*)d_out;

  char* ws = (char*)d_ws;
  u16* R1 = (u16*)ws;                  // 50,331,648 B : Wqkv_t, then attn
  u16* R2 = (u16*)(ws + 50331648);     // 50,331,648 B : qkv, then Wo_t
  u16* R3 = (u16*)(ws + 100663296);    // 33,554,432 B : hidden_bf16, then Vt
  // total 128 MiB

  // 1. hidden fp32 -> bf16
  conv_kernel<<<16384, 256, 0, stream>>>(hidden, R3);
  // 2. Wqkv [4096][6144] -> [6144][4096] bf16
  transconv_kernel<<<dim3(6144 / 32, 4096 / 32), 256, 0, stream>>>(Wqkv, R1, 4096, 6144);
  // 3. qkv = hidden x Wqkv  (bf16 out)
  gemm_kernel<u16><<<dim3(48, 32), 256, 0, stream>>>(R3, R1, R2, 4096, 6144, 4096);
  // 4. RoPE on q,k
  rope_kernel<<<40960, 256, 0, stream>>>(R2, cosb, sinb);
  // 5. V -> Vt[b][kvh][d][S]
  vtrans_kernel<<<4096, 256, 0, stream>>>(R2, R3);
  // 6. flash attention -> attn (bf16)
  flash_kernel<<<1024, 256, 0, stream>>>(R2, R3, R1);
  // 7. Wo [4096][4096] -> [4096][4096]^T bf16
  transconv_kernel<<<dim3(4096 / 32, 4096 / 32), 256, 0, stream>>>(Wo, R2, 4096, 4096);
  // 8. out = attn x Wo (fp32 out)
  gemm_kernel<float><<<dim3(32, 32), 256, 0, stream>>>(R1, R2, out, 4096, 4096, 4096);
}

// Round 2
// 1037.663 us; speedup vs baseline: 1.3140x; 1.3140x over previous
//
#include <hip/hip_runtime.h>

typedef unsigned short u16;
typedef __bf16 bf16x8 __attribute__((ext_vector_type(8)));
typedef float f32x4 __attribute__((ext_vector_type(4)));
typedef u16 u16x4 __attribute__((ext_vector_type(4)));

#define SEQ 2048
#define NQKV 6144
#define HID 4096

__device__ inline u16 f2bf(float f) {
  union { float f; unsigned u; } x; x.f = f;
  unsigned r = x.u + 0x7fffu + ((x.u >> 16) & 1u);  // RNE
  return (u16)(r >> 16);
}
__device__ inline float bf2f(u16 u) {
  union { unsigned u; float f; } x; x.u = ((unsigned)u) << 16;
  return x.f;
}
__device__ inline f32x4 mfma16(bf16x8 a, bf16x8 b, f32x4 c) {
  return __builtin_amdgcn_mfma_f32_16x16x32_bf16(a, b, c, 0, 0, 0);
}
__device__ inline void gload16(const void* g, void* l) {
  __builtin_amdgcn_global_load_lds((const __attribute__((address_space(1))) void*)g,
                                   (__attribute__((address_space(3))) void*)l,
                                   16, 0, 0);
}

// ---------- fp32 -> bf16 contiguous convert ----------
__global__ __launch_bounds__(256) void conv_kernel(const float* __restrict__ in,
                                                   u16* __restrict__ out) {
  int i = (blockIdx.x * 256 + threadIdx.x) * 4;
  float4 v = *(const float4*)(in + i);
  u16x4 o;
  o[0] = f2bf(v.x); o[1] = f2bf(v.y); o[2] = f2bf(v.z); o[3] = f2bf(v.w);
  *(u16x4*)(out + i) = o;
}

// ---------- fp32 [R][C] -> bf16 [C][R] transpose-convert ----------
__global__ __launch_bounds__(256) void transconv_kernel(const float* __restrict__ in,
                                                        u16* __restrict__ out,
                                                        int R, int C) {
  __shared__ u16 tile[32][33];
  int c0 = blockIdx.x * 32, r0 = blockIdx.y * 32;
  int tx = threadIdx.x & 31, ty = threadIdx.x >> 5;
  for (int i = 0; i < 4; ++i)
    tile[ty + 8 * i][tx] = f2bf(in[(size_t)(r0 + ty + 8 * i) * C + c0 + tx]);
  __syncthreads();
  for (int i = 0; i < 4; ++i)
    out[(size_t)(c0 + ty + 8 * i) * R + r0 + tx] = tile[tx][ty + 8 * i];
}

// ---------- bf16 GEMM: A[M][K] x Bt[N][K] -> C[M][N]  (m97 structure) ----------
__device__ inline void store_out(u16* p, float v) { *p = f2bf(v); }
__device__ inline void store_out(float* p, float v) { *p = v; }

template <typename OutT>
__global__ __launch_bounds__(256) void gemm_kernel(const u16* __restrict__ A,
                                                   const u16* __restrict__ Bt,
                                                   OutT* __restrict__ C,
                                                   int M, int N, int K) {
  __shared__ __align__(16) u16 As[128 * 32];
  __shared__ __align__(16) u16 Bs[128 * 32];
  int row0 = blockIdx.y * 128, col0 = blockIdx.x * 128;
  int t = threadIdx.x, w = t >> 6, l = t & 63;
  int wm = w >> 1, wn = w & 1;        // 2x2 waves -> 64x64 each
  int lo = l & 15, hi = l >> 4;
  f32x4 acc[4][4] = {};
  for (int kt = 0; kt < K; kt += 32) {
    for (int c = 0; c < 2; ++c) {
      int ch = w * 2 + c;             // 8 x 1KB chunks each for As/Bs
      gload16(A + (size_t)(row0 + ch * 16 + (l >> 2)) * K + kt + (l & 3) * 8, &As[ch * 512]);
      gload16(Bt + (size_t)(col0 + ch * 16 + (l >> 2)) * K + kt + (l & 3) * 8, &Bs[ch * 512]);
    }
    __syncthreads();
    bf16x8 af[4], bfr[4];
    for (int m = 0; m < 4; ++m)
      af[m] = *(const bf16x8*)&As[(wm * 64 + m * 16 + lo) * 32 + hi * 8];
    for (int n = 0; n < 4; ++n)
      bfr[n] = *(const bf16x8*)&Bs[(wn * 64 + n * 16 + lo) * 32 + hi * 8];
    for (int m = 0; m < 4; ++m)
      for (int n = 0; n < 4; ++n)
        acc[m][n] = mfma16(af[m], bfr[n], acc[m][n]);
    __syncthreads();
  }
  for (int m = 0; m < 4; ++m)
    for (int n = 0; n < 4; ++n)
      for (int r = 0; r < 4; ++r) {
        int row = row0 + wm * 64 + m * 16 + hi * 4 + r;  // C/D: row=(l>>4)*4+r
        int col = col0 + wn * 64 + n * 16 + lo;          //      col=l&15
        store_out(&C[(size_t)row * N + col], acc[m][n][r]);
      }
}

// ---------- RoPE in place on q,k regions of qkv ----------
__global__ __launch_bounds__(256) void rope_kernel(u16* __restrict__ qkv,
                                                   const float* __restrict__ cosb,
                                                   const float* __restrict__ sinb) {
  int idx = blockIdx.x * 256 + threadIdx.x;   // (m, head<40, d<64)
  int d = idx & 63;
  int head = (idx >> 6) % 40;
  int m = idx / (64 * 40);
  int s = m & (SEQ - 1);
  int col = head < 32 ? head * 128 : 4096 + (head - 32) * 128;
  u16* p = qkv + (size_t)m * NQKV + col;
  float x1 = bf2f(p[d]), x2 = bf2f(p[d + 64]);
  float c = cosb[s * 64 + d], sn = sinb[s * 64 + d];
  p[d] = f2bf(x1 * c - x2 * sn);
  p[d + 64] = f2bf(x2 * c + x1 * sn);
}

// ---------- V transpose: qkv v-region -> Vt[b][kvh][d][S] ----------
__global__ __launch_bounds__(256) void vtrans_kernel(const u16* __restrict__ qkv,
                                                     u16* __restrict__ Vt) {
  __shared__ u16 tile[32][33];
  int bid = blockIdx.x;
  int dt = bid & 3;
  int st = (bid >> 2) & 63;
  int bk = bid >> 8;               // b*8+kvh
  int b = bk >> 3, kvh = bk & 7;
  int tx = threadIdx.x & 31, ty = threadIdx.x >> 5;
  for (int i = 0; i < 4; ++i) {
    int s = st * 32 + ty + 8 * i;
    tile[ty + 8 * i][tx] = qkv[(size_t)(b * SEQ + s) * NQKV + 5120 + kvh * 128 + dt * 32 + tx];
  }
  __syncthreads();
  for (int i = 0; i < 4; ++i) {
    int d = dt * 32 + ty + 8 * i;
    Vt[((size_t)bk * 128 + d) * SEQ + st * 32 + tx] = tile[tx][ty + 8 * i];
  }
}

// ---------- flash attention: 4 waves/block, 32 q-rows/wave, KBLK=64 ----------
// Heavy-first dispatch: qc = 15 - (bid>>6) so the 64 longest (32-k-tile) blocks
// launch first and light blocks backfill -> fixes causal-tail starvation
// (R1: OccupancyPercent 6.3%, ~2 waves/CU avg, 834us).
__global__ __launch_bounds__(256) void flash_kernel(const u16* __restrict__ qkv,
                                                    const u16* __restrict__ Vt,
                                                    u16* __restrict__ attn) {
  const float scale = 0.08838834764831843f;  // 1/sqrt(128)
  int bid = blockIdx.x;
  int bh = bid & 63;                // (b,h) fastest: heavy tiles spread over CUs
  int qc = 15 - (bid >> 6);         // heavy first
  int h = bh & 31;
  int b = bh >> 5;
  int w = threadIdx.x >> 6, l = threadIdx.x & 63;
  int lo = l & 15, hi = l >> 4;
  int q0 = qc * 128 + w * 32;
  int kvh = h >> 2;

  __shared__ __align__(16) u16 P_lds[4][32][72];  // per-wave P, padded rows
  u16(*P)[72] = P_lds[w];

  bf16x8 aq[2][4];
  for (int s2 = 0; s2 < 2; ++s2) {
    const u16* qr = qkv + (size_t)(b * SEQ + q0 + s2 * 16 + lo) * NQKV + h * 128 + hi * 8;
    for (int dk = 0; dk < 4; ++dk) aq[s2][dk] = *(const bf16x8*)(qr + dk * 32);
  }
  f32x4 o[2][8] = {};
  float mreg[2][4], lreg[2][4];
  for (int s2 = 0; s2 < 2; ++s2)
    for (int r = 0; r < 4; ++r) { mreg[s2][r] = -1e30f; lreg[s2][r] = 0.f; }

  const u16* vtb = Vt + (size_t)(b * 8 + kvh) * 128 * SEQ;
  int ktmax = q0 >> 6;
  for (int kt = 0; kt <= ktmax; ++kt) {
    // ---- scores: S = Q K^T ----
    f32x4 sc[2][4];
    for (int ct = 0; ct < 4; ++ct) {
      bf16x8 kf[4];
      const u16* kr = qkv + (size_t)(b * SEQ + kt * 64 + ct * 16 + lo) * NQKV + 4096 + kvh * 128 + hi * 8;
      for (int dk = 0; dk < 4; ++dk) kf[dk] = *(const bf16x8*)(kr + dk * 32);
      for (int s2 = 0; s2 < 2; ++s2) {
        f32x4 a = {0.f, 0.f, 0.f, 0.f};
        for (int dk = 0; dk < 4; ++dk) a = mfma16(aq[s2][dk], kf[dk], a);
        sc[s2][ct] = a;
      }
    }
    bool masked = (kt == ktmax);
    // ---- online softmax ----
    for (int s2 = 0; s2 < 2; ++s2) {
      float pv[4][4];
      float tm[4] = {-1e30f, -1e30f, -1e30f, -1e30f};
      for (int ct = 0; ct < 4; ++ct)
        for (int r = 0; r < 4; ++r) {
          float v = sc[s2][ct][r] * scale;
          if (masked && (kt * 64 + ct * 16 + lo > q0 + s2 * 16 + hi * 4 + r)) v = -1e30f;
          pv[ct][r] = v;
          tm[r] = fmaxf(tm[r], v);
        }
      for (int r = 0; r < 4; ++r) {
        float t = tm[r];
        t = fmaxf(t, __shfl_xor(t, 1));
        t = fmaxf(t, __shfl_xor(t, 2));
        t = fmaxf(t, __shfl_xor(t, 4));
        t = fmaxf(t, __shfl_xor(t, 8));
        float mnew = fmaxf(mreg[s2][r], t);
        float alpha = __expf(mreg[s2][r] - mnew);
        mreg[s2][r] = mnew;
        float rs = 0.f;
        for (int ct = 0; ct < 4; ++ct) {
          float p = __expf(pv[ct][r] - mnew);
          pv[ct][r] = p;
          rs += p;
        }
        rs += __shfl_xor(rs, 1);
        rs += __shfl_xor(rs, 2);
        rs += __shfl_xor(rs, 4);
        rs += __shfl_xor(rs, 8);
        lreg[s2][r] = lreg[s2][r] * alpha + rs;
        for (int dt = 0; dt < 8; ++dt) o[s2][dt][r] *= alpha;
        for (int ct = 0; ct < 4; ++ct)
          P[s2 * 16 + hi * 4 + r][ct * 16 + lo] = f2bf(pv[ct][r]);
      }
    }
    asm volatile("s_waitcnt lgkmcnt(0)" ::: "memory");  // P writes visible before reads
    // ---- O += P V ----
    for (int kk = 0; kk < 2; ++kk) {
      bf16x8 ap[2];
      for (int s2 = 0; s2 < 2; ++s2)
        ap[s2] = *(const bf16x8*)&P[s2 * 16 + lo][kk * 32 + hi * 8];
      for (int dt = 0; dt < 8; ++dt) {
        bf16x8 vf = *(const bf16x8*)(vtb + (size_t)(dt * 16 + lo) * SEQ + kt * 64 + kk * 32 + hi * 8);
        for (int s2 = 0; s2 < 2; ++s2) o[s2][dt] = mfma16(ap[s2], vf, o[s2][dt]);
      }
    }
  }
  // ---- epilogue ----
  for (int s2 = 0; s2 < 2; ++s2)
    for (int dt = 0; dt < 8; ++dt)
      for (int r = 0; r < 4; ++r) {
        float v2 = o[s2][dt][r] / lreg[s2][r];
        attn[(size_t)(b * SEQ + q0 + s2 * 16 + hi * 4 + r) * 4096 + h * 128 + dt * 16 + lo] = f2bf(v2);
      }
}

extern "C" void kernel_launch(void* const* d_in, const int* in_sizes, int n_in,
                              void* d_out, int out_size, void* d_ws, size_t ws_size,
                              hipStream_t stream) {
  const float* hidden = (const float*)d_in[0];
  const float* Wqkv = (const float*)d_in[1];
  const float* Wo = (const float*)d_in[2];
  const float* cosb = (const float*)d_in[3];
  const float* sinb = (const float*)d_in[4];
  // d_in[5] (attention_mask) is exactly causal triu(-1e9): applied analytically.
  float* out = (float*)d_out;

  char* ws = (char*)d_ws;
  u16* R1 = (u16*)ws;                  // 50,331,648 B : Wqkv_t, then attn
  u16* R2 = (u16*)(ws + 50331648);     // 50,331,648 B : qkv, then Wo_t
  u16* R3 = (u16*)(ws + 100663296);    // 33,554,432 B : hidden_bf16, then Vt
  // total 128 MiB

  // 1. hidden fp32 -> bf16
  conv_kernel<<<16384, 256, 0, stream>>>(hidden, R3);
  // 2. Wqkv [4096][6144] -> [6144][4096] bf16
  transconv_kernel<<<dim3(6144 / 32, 4096 / 32), 256, 0, stream>>>(Wqkv, R1, 4096, 6144);
  // 3. qkv = hidden x Wqkv  (bf16 out)
  gemm_kernel<u16><<<dim3(48, 32), 256, 0, stream>>>(R3, R1, R2, 4096, 6144, 4096);
  // 4. RoPE on q,k
  rope_kernel<<<40960, 256, 0, stream>>>(R2, cosb, sinb);
  // 5. V -> Vt[b][kvh][d][S]
  vtrans_kernel<<<4096, 256, 0, stream>>>(R2, R3);
  // 6. flash attention -> attn (bf16)
  flash_kernel<<<1024, 256, 0, stream>>>(R2, R3, R1);
  // 7. Wo [4096][4096] -> [4096][4096]^T bf16
  transconv_kernel<<<dim3(4096 / 32, 4096 / 32), 256, 0, stream>>>(Wo, R2, 4096, 4096);
  // 8. out = attn x Wo (fp32 out)
  gemm_kernel<float><<<dim3(32, 32), 256, 0, stream>>>(R1, R2, out, 4096, 4096, 4096);
}

// Round 3
// 803.723 us; speedup vs baseline: 1.6965x; 1.2911x over previous
//
#include <hip/hip_runtime.h>

typedef unsigned short u16;
typedef __bf16 bf16x8 __attribute__((ext_vector_type(8)));
typedef float f32x4 __attribute__((ext_vector_type(4)));
typedef u16 u16x4 __attribute__((ext_vector_type(4)));

#define SEQ 2048
#define NQKV 6144
#define HID 4096

__device__ inline u16 f2bf(float f) {
  union { float f; unsigned u; } x; x.f = f;
  unsigned r = x.u + 0x7fffu + ((x.u >> 16) & 1u);  // RNE
  return (u16)(r >> 16);
}
__device__ inline float bf2f(u16 u) {
  union { unsigned u; float f; } x; x.u = ((unsigned)u) << 16;
  return x.f;
}
__device__ inline f32x4 mfma16(bf16x8 a, bf16x8 b, f32x4 c) {
  return __builtin_amdgcn_mfma_f32_16x16x32_bf16(a, b, c, 0, 0, 0);
}
__device__ inline void gload16(const void* g, void* l) {
  __builtin_amdgcn_global_load_lds((const __attribute__((address_space(1))) void*)g,
                                   (__attribute__((address_space(3))) void*)l,
                                   16, 0, 0);
}

// ---------- fp32 -> bf16 contiguous convert ----------
__global__ __launch_bounds__(256) void conv_kernel(const float* __restrict__ in,
                                                   u16* __restrict__ out) {
  int i = (blockIdx.x * 256 + threadIdx.x) * 4;
  float4 v = *(const float4*)(in + i);
  u16x4 o;
  o[0] = f2bf(v.x); o[1] = f2bf(v.y); o[2] = f2bf(v.z); o[3] = f2bf(v.w);
  *(u16x4*)(out + i) = o;
}

// ---------- fp32 [R][C] -> bf16 [C][R] transpose-convert ----------
__global__ __launch_bounds__(256) void transconv_kernel(const float* __restrict__ in,
                                                        u16* __restrict__ out,
                                                        int R, int C) {
  __shared__ u16 tile[32][33];
  int c0 = blockIdx.x * 32, r0 = blockIdx.y * 32;
  int tx = threadIdx.x & 31, ty = threadIdx.x >> 5;
  for (int i = 0; i < 4; ++i)
    tile[ty + 8 * i][tx] = f2bf(in[(size_t)(r0 + ty + 8 * i) * C + c0 + tx]);
  __syncthreads();
  for (int i = 0; i < 4; ++i)
    out[(size_t)(c0 + ty + 8 * i) * R + r0 + tx] = tile[tx][ty + 8 * i];
}

// ---------- bf16 GEMM: A[M][K] x Bt[N][K] -> C[M][N]  (m97 structure) ----------
__device__ inline void store_out(u16* p, float v) { *p = f2bf(v); }
__device__ inline void store_out(float* p, float v) { *p = v; }

template <typename OutT>
__global__ __launch_bounds__(256) void gemm_kernel(const u16* __restrict__ A,
                                                   const u16* __restrict__ Bt,
                                                   OutT* __restrict__ C,
                                                   int M, int N, int K) {
  __shared__ __align__(16) u16 As[128 * 32];
  __shared__ __align__(16) u16 Bs[128 * 32];
  int row0 = blockIdx.y * 128, col0 = blockIdx.x * 128;
  int t = threadIdx.x, w = t >> 6, l = t & 63;
  int wm = w >> 1, wn = w & 1;        // 2x2 waves -> 64x64 each
  int lo = l & 15, hi = l >> 4;
  f32x4 acc[4][4] = {};
  for (int kt = 0; kt < K; kt += 32) {
    for (int c = 0; c < 2; ++c) {
      int ch = w * 2 + c;             // 8 x 1KB chunks each for As/Bs
      gload16(A + (size_t)(row0 + ch * 16 + (l >> 2)) * K + kt + (l & 3) * 8, &As[ch * 512]);
      gload16(Bt + (size_t)(col0 + ch * 16 + (l >> 2)) * K + kt + (l & 3) * 8, &Bs[ch * 512]);
    }
    __syncthreads();
    bf16x8 af[4], bfr[4];
    for (int m = 0; m < 4; ++m)
      af[m] = *(const bf16x8*)&As[(wm * 64 + m * 16 + lo) * 32 + hi * 8];
    for (int n = 0; n < 4; ++n)
      bfr[n] = *(const bf16x8*)&Bs[(wn * 64 + n * 16 + lo) * 32 + hi * 8];
    for (int m = 0; m < 4; ++m)
      for (int n = 0; n < 4; ++n)
        acc[m][n] = mfma16(af[m], bfr[n], acc[m][n]);
    __syncthreads();
  }
  for (int m = 0; m < 4; ++m)
    for (int n = 0; n < 4; ++n)
      for (int r = 0; r < 4; ++r) {
        int row = row0 + wm * 64 + m * 16 + hi * 4 + r;  // C/D: row=(l>>4)*4+r
        int col = col0 + wn * 64 + n * 16 + lo;          //      col=l&15
        store_out(&C[(size_t)row * N + col], acc[m][n][r]);
      }
}

// ---------- RoPE in place on q,k regions of qkv ----------
__global__ __launch_bounds__(256) void rope_kernel(u16* __restrict__ qkv,
                                                   const float* __restrict__ cosb,
                                                   const float* __restrict__ sinb) {
  int idx = blockIdx.x * 256 + threadIdx.x;   // (m, head<40, d<64)
  int d = idx & 63;
  int head = (idx >> 6) % 40;
  int m = idx / (64 * 40);
  int s = m & (SEQ - 1);
  int col = head < 32 ? head * 128 : 4096 + (head - 32) * 128;
  u16* p = qkv + (size_t)m * NQKV + col;
  float x1 = bf2f(p[d]), x2 = bf2f(p[d + 64]);
  float c = cosb[s * 64 + d], sn = sinb[s * 64 + d];
  p[d] = f2bf(x1 * c - x2 * sn);
  p[d + 64] = f2bf(x2 * c + x1 * sn);
}

// ---------- V transpose: qkv v-region -> Vt[b][kvh][d][S] ----------
__global__ __launch_bounds__(256) void vtrans_kernel(const u16* __restrict__ qkv,
                                                     u16* __restrict__ Vt) {
  __shared__ u16 tile[32][33];
  int bid = blockIdx.x;
  int dt = bid & 3;
  int st = (bid >> 2) & 63;
  int bk = bid >> 8;               // b*8+kvh
  int b = bk >> 3, kvh = bk & 7;
  int tx = threadIdx.x & 31, ty = threadIdx.x >> 5;
  for (int i = 0; i < 4; ++i) {
    int s = st * 32 + ty + 8 * i;
    tile[ty + 8 * i][tx] = qkv[(size_t)(b * SEQ + s) * NQKV + 5120 + kvh * 128 + dt * 32 + tx];
  }
  __syncthreads();
  for (int i = 0; i < 4; ++i) {
    int d = dt * 32 + ty + 8 * i;
    Vt[((size_t)bk * 128 + d) * SEQ + st * 32 + tx] = tile[tx][ty + 8 * i];
  }
}

// ---------- flash attention: 4 waves/block, 32 q-rows/wave, KBLK=64 ----------
// R2 diagnosis: per-lane K/V gathers split into 16 cache-line transactions per
// wave instr, re-requested by all 4 waves -> ~2048 line-reqs per block-k-tile,
// TA/L1-rate-bound (all counters <20%). Fix: stage K,Vt tiles in LDS once per
// block via global_load_lds (coalesced, 512 lines), XOR-swizzled chunks
// (pre-swizzled GLOBAL src + linear LDS dest + swizzled ds_read — m173/G4).
__global__ __launch_bounds__(256) void flash_kernel(const u16* __restrict__ qkv,
                                                    const u16* __restrict__ Vt,
                                                    u16* __restrict__ attn) {
  const float scale = 0.08838834764831843f;  // 1/sqrt(128)
  int bid = blockIdx.x;
  int bh = bid & 63;                // (b,h) fastest: heavy tiles spread over CUs
  int qc = 15 - (bid >> 6);         // heavy first
  int h = bh & 31;
  int b = bh >> 5;
  int w = threadIdx.x >> 6, l = threadIdx.x & 63;
  int lo = l & 15, hi = l >> 4;
  int q0 = qc * 128 + w * 32;
  int kvh = h >> 2;

  __shared__ __align__(16) u16 Ks[64 * 128];      // [row][chunk^=(row&7)] 16B chunks
  __shared__ __align__(16) u16 Vs[128 * 64];      // [d]  [chunk^=(d&7)]   16B chunks
  __shared__ __align__(16) u16 P_lds[4][32][72];  // per-wave P, padded rows
  u16(*P)[72] = P_lds[w];

  bf16x8 aq[2][4];
  for (int s2 = 0; s2 < 2; ++s2) {
    const u16* qr = qkv + (size_t)(b * SEQ + q0 + s2 * 16 + lo) * NQKV + h * 128 + hi * 8;
    for (int dk = 0; dk < 4; ++dk) aq[s2][dk] = *(const bf16x8*)(qr + dk * 32);
  }
  f32x4 o[2][8] = {};
  float mreg[2][4], lreg[2][4];
  for (int s2 = 0; s2 < 2; ++s2)
    for (int r = 0; r < 4; ++r) { mreg[s2][r] = -1e30f; lreg[s2][r] = 0.f; }

  const u16* kb = qkv + (size_t)(b * SEQ) * NQKV + 4096 + kvh * 128;
  const u16* vtb = Vt + (size_t)(b * 8 + kvh) * 128 * SEQ;
  int ktend = 2 * qc + 1;            // block-uniform k-loop
  int myktmax = 2 * qc + (w >> 1);   // this wave's causal limit

  for (int kt = 0; kt <= ktend; ++kt) {
    // ---- stage K tile: 64 rows x 256B; 16 wave-instrs, 4/wave ----
    for (int i = 0; i < 4; ++i) {
      int ck = w * 4 + i;
      int r = ck * 4 + (l >> 4);     // 4 rows per 1KB chunk, 16 lanes/row
      int c = l & 15;                // 16B chunk within row
      gload16(kb + (size_t)(kt * 64 + r) * NQKV + (size_t)((c ^ (r & 7)) * 8),
              &Ks[ck * 512]);
    }
    // ---- stage Vt tile: 128 rows x 128B; 16 wave-instrs, 4/wave ----
    for (int i = 0; i < 4; ++i) {
      int ck = w * 4 + i;
      int r = ck * 8 + (l >> 3);     // 8 rows per 1KB chunk, 8 lanes/row
      int c = l & 7;
      gload16(vtb + (size_t)r * SEQ + kt * 64 + ((c ^ (r & 7)) * 8),
              &Vs[ck * 512]);
    }
    __syncthreads();                 // drains vmcnt, tiles ready

    bool active = (kt <= myktmax);
    if (active) {
      // ---- scores: S = Q K^T (K from swizzled LDS) ----
      f32x4 sc[2][4];
      for (int ct = 0; ct < 4; ++ct) {
        bf16x8 kf[4];
        int row = ct * 16 + lo;
        for (int dk = 0; dk < 4; ++dk)
          kf[dk] = *(const bf16x8*)&Ks[row * 128 + (((dk * 4 + hi) ^ (row & 7)) * 8)];
        for (int s2 = 0; s2 < 2; ++s2) {
          f32x4 a = {0.f, 0.f, 0.f, 0.f};
          for (int dk = 0; dk < 4; ++dk) a = mfma16(aq[s2][dk], kf[dk], a);
          sc[s2][ct] = a;
        }
      }
      bool masked = (kt == myktmax);
      // ---- online softmax ----
      for (int s2 = 0; s2 < 2; ++s2) {
        float pv[4][4];
        float tm[4] = {-1e30f, -1e30f, -1e30f, -1e30f};
        for (int ct = 0; ct < 4; ++ct)
          for (int r = 0; r < 4; ++r) {
            float v = sc[s2][ct][r] * scale;
            if (masked && (kt * 64 + ct * 16 + lo > q0 + s2 * 16 + hi * 4 + r)) v = -1e30f;
            pv[ct][r] = v;
            tm[r] = fmaxf(tm[r], v);
          }
        for (int r = 0; r < 4; ++r) {
          float t = tm[r];
          t = fmaxf(t, __shfl_xor(t, 1));
          t = fmaxf(t, __shfl_xor(t, 2));
          t = fmaxf(t, __shfl_xor(t, 4));
          t = fmaxf(t, __shfl_xor(t, 8));
          float mnew = fmaxf(mreg[s2][r], t);
          float alpha = __expf(mreg[s2][r] - mnew);
          mreg[s2][r] = mnew;
          float rs = 0.f;
          for (int ct = 0; ct < 4; ++ct) {
            float p = __expf(pv[ct][r] - mnew);
            pv[ct][r] = p;
            rs += p;
          }
          rs += __shfl_xor(rs, 1);
          rs += __shfl_xor(rs, 2);
          rs += __shfl_xor(rs, 4);
          rs += __shfl_xor(rs, 8);
          lreg[s2][r] = lreg[s2][r] * alpha + rs;
          for (int dt = 0; dt < 8; ++dt) o[s2][dt][r] *= alpha;
          for (int ct = 0; ct < 4; ++ct)
            P[s2 * 16 + hi * 4 + r][ct * 16 + lo] = f2bf(pv[ct][r]);
        }
      }
      asm volatile("s_waitcnt lgkmcnt(0)" ::: "memory");  // P visible (per-wave)
      // ---- O += P V (V from swizzled LDS) ----
      for (int kk = 0; kk < 2; ++kk) {
        bf16x8 ap[2];
        for (int s2 = 0; s2 < 2; ++s2)
          ap[s2] = *(const bf16x8*)&P[s2 * 16 + lo][kk * 32 + hi * 8];
        for (int dt = 0; dt < 8; ++dt) {
          int row = dt * 16 + lo;
          bf16x8 vf = *(const bf16x8*)&Vs[row * 64 + (((kk * 4 + hi) ^ (row & 7)) * 8)];
          for (int s2 = 0; s2 < 2; ++s2) o[s2][dt] = mfma16(ap[s2], vf, o[s2][dt]);
        }
      }
    }
    __syncthreads();                 // all waves done before next stage
  }
  // ---- epilogue ----
  for (int s2 = 0; s2 < 2; ++s2)
    for (int dt = 0; dt < 8; ++dt)
      for (int r = 0; r < 4; ++r) {
        float v2 = o[s2][dt][r] / lreg[s2][r];
        attn[(size_t)(b * SEQ + q0 + s2 * 16 + hi * 4 + r) * 4096 + h * 128 + dt * 16 + lo] = f2bf(v2);
      }
}

extern "C" void kernel_launch(void* const* d_in, const int* in_sizes, int n_in,
                              void* d_out, int out_size, void* d_ws, size_t ws_size,
                              hipStream_t stream) {
  const float* hidden = (const float*)d_in[0];
  const float* Wqkv = (const float*)d_in[1];
  const float* Wo = (const float*)d_in[2];
  const float* cosb = (const float*)d_in[3];
  const float* sinb = (const float*)d_in[4];
  // d_in[5] (attention_mask) is exactly causal triu(-1e9): applied analytically.
  float* out = (float*)d_out;

  char* ws = (char*)d_ws;
  u16* R1 = (u16*)ws;                  // 50,331,648 B : Wqkv_t, then attn
  u16* R2 = (u16*)(ws + 50331648);     // 50,331,648 B : qkv, then Wo_t
  u16* R3 = (u16*)(ws + 100663296);    // 33,554,432 B : hidden_bf16, then Vt
  // total 128 MiB

  // 1. hidden fp32 -> bf16
  conv_kernel<<<16384, 256, 0, stream>>>(hidden, R3);
  // 2. Wqkv [4096][6144] -> [6144][4096] bf16
  transconv_kernel<<<dim3(6144 / 32, 4096 / 32), 256, 0, stream>>>(Wqkv, R1, 4096, 6144);
  // 3. qkv = hidden x Wqkv  (bf16 out)
  gemm_kernel<u16><<<dim3(48, 32), 256, 0, stream>>>(R3, R1, R2, 4096, 6144, 4096);
  // 4. RoPE on q,k
  rope_kernel<<<40960, 256, 0, stream>>>(R2, cosb, sinb);
  // 5. V -> Vt[b][kvh][d][S]
  vtrans_kernel<<<4096, 256, 0, stream>>>(R2, R3);
  // 6. flash attention -> attn (bf16)
  flash_kernel<<<1024, 256, 0, stream>>>(R2, R3, R1);
  // 7. Wo [4096][4096] -> [4096][4096]^T bf16
  transconv_kernel<<<dim3(4096 / 32, 4096 / 32), 256, 0, stream>>>(Wo, R2, 4096, 4096);
  // 8. out = attn x Wo (fp32 out)
  gemm_kernel<float><<<dim3(32, 32), 256, 0, stream>>>(R1, R2, out, 4096, 4096, 4096);
}

// Round 4
// 777.319 us; speedup vs baseline: 1.7542x; 1.0340x over previous
//
#include <hip/hip_runtime.h>

typedef unsigned short u16;
typedef __bf16 bf16x8 __attribute__((ext_vector_type(8)));
typedef float f32x4 __attribute__((ext_vector_type(4)));
typedef u16 u16x4 __attribute__((ext_vector_type(4)));

#define SEQ 2048
#define NQKV 6144
#define HID 4096

__device__ inline u16 f2bf(float f) {
  union { float f; unsigned u; } x; x.f = f;
  unsigned r = x.u + 0x7fffu + ((x.u >> 16) & 1u);  // RNE
  return (u16)(r >> 16);
}
__device__ inline float bf2f(u16 u) {
  union { unsigned u; float f; } x; x.u = ((unsigned)u) << 16;
  return x.f;
}
__device__ inline f32x4 mfma16(bf16x8 a, bf16x8 b, f32x4 c) {
  return __builtin_amdgcn_mfma_f32_16x16x32_bf16(a, b, c, 0, 0, 0);
}
__device__ inline void gload16(const void* g, void* l) {
  __builtin_amdgcn_global_load_lds((const __attribute__((address_space(1))) void*)g,
                                   (__attribute__((address_space(3))) void*)l,
                                   16, 0, 0);
}

// ---------- fp32 -> bf16 contiguous convert ----------
__global__ __launch_bounds__(256) void conv_kernel(const float* __restrict__ in,
                                                   u16* __restrict__ out) {
  int i = (blockIdx.x * 256 + threadIdx.x) * 4;
  float4 v = *(const float4*)(in + i);
  u16x4 o;
  o[0] = f2bf(v.x); o[1] = f2bf(v.y); o[2] = f2bf(v.z); o[3] = f2bf(v.w);
  *(u16x4*)(out + i) = o;
}

// ---------- fp32 [R][C] -> bf16 [C][R] transpose-convert ----------
__global__ __launch_bounds__(256) void transconv_kernel(const float* __restrict__ in,
                                                        u16* __restrict__ out,
                                                        int R, int C) {
  __shared__ u16 tile[32][33];
  int c0 = blockIdx.x * 32, r0 = blockIdx.y * 32;
  int tx = threadIdx.x & 31, ty = threadIdx.x >> 5;
  for (int i = 0; i < 4; ++i)
    tile[ty + 8 * i][tx] = f2bf(in[(size_t)(r0 + ty + 8 * i) * C + c0 + tx]);
  __syncthreads();
  for (int i = 0; i < 4; ++i)
    out[(size_t)(c0 + ty + 8 * i) * R + r0 + tx] = tile[tx][ty + 8 * i];
}

// ---------- bf16 GEMM: A[M][K] x Bt[N][K] -> C[M][N] ----------
// 8-phase-style schedule (guide §5/§5.5): BM=128 BN=256 BK=32, 8 waves (2Mx4N,
// wave tile 64x64), depth-4 LDS ring (96 KiB) -> staging 3 tiles ahead with
// counted vmcnt(6) (never 0 in loop), raw s_barrier (NOT __syncthreads which
// drains vmcnt0), setprio around MFMA clusters (T5), XCD-bijective block
// swizzle (T1), 2-way-free bank swizzle: chunk c ^= (row>>1)&3 applied on
// pre-swizzled GLOBAL source + swizzled ds_read (linear LDS dest, m173/G4).
// Race safety: buffer (t+3)&3 written at iter t; its readers (tile t-1)
// finished at iter t-1's last barrier. Visibility: each wave passes its own
// vmcnt(6) before the barrier => all waves' tile-t loads landed.
__device__ inline void store_out(u16* p, float v) { *p = f2bf(v); }
__device__ inline void store_out(float* p, float v) { *p = v; }

template <typename OutT>
__global__ __launch_bounds__(512, 2) void gemm_kernel(const u16* __restrict__ A,
                                                      const u16* __restrict__ Bt,
                                                      OutT* __restrict__ C,
                                                      int M, int N, int K, int nby) {
  __shared__ __align__(16) u16 As[4][128 * 32];
  __shared__ __align__(16) u16 Bs[4][256 * 32];
  int nwg = gridDim.x;                      // multiple of 8
  int bid = blockIdx.x;
  int s = (bid & 7) * (nwg >> 3) + (bid >> 3);   // XCD-contiguous, bijective
  int by = s % nby, bx = s / nby;
  int row0 = by * 128, col0 = bx * 256;
  int tid = threadIdx.x, w = tid >> 6, l = tid & 63;
  int wm = w >> 2, wn = w & 3;              // wave tile 64x64
  int lo = l & 15, hi = l >> 4;
  // staging lane constants: lane l stages row (..)+ (l>>2), source chunk
  // (l&3)^((l>>3)&3)  [= (l&3)^((r>>1)&3) since r = 16*a + (l>>2)]
  int lr = l >> 2;
  int lc = (l & 3) ^ ((l >> 3) & 3);
  const u16* Ab = A + (size_t)row0 * K;
  const u16* Bb = Bt + (size_t)col0 * K;
  int nkt = K >> 5;

  f32x4 acc[4][4] = {};

#define STAGE_A(tt)                                                          \
  gload16(Ab + (size_t)(w * 16 + lr) * K + (tt) * 32 + lc * 8,               \
          &As[(tt) & 3][w * 64 * 8])
#define STAGE_B(tt, j)                                                       \
  gload16(Bb + (size_t)((j) * 128 + w * 16 + lr) * K + (tt) * 32 + lc * 8,   \
          &Bs[(tt) & 3][((j) * 512 + w * 64) * 8])
#define RD_A(cur, fm, dst)                                                   \
  { int r = wm * 64 + (fm) * 16 + lo;                                        \
    dst = *(const bf16x8*)&As[cur][r * 32 + ((hi ^ ((r >> 1) & 3)) * 8)]; }
#define RD_B(cur, fn, dst)                                                   \
  { int r = wn * 64 + (fn) * 16 + lo;                                        \
    dst = *(const bf16x8*)&Bs[cur][r * 32 + ((hi ^ ((r >> 1) & 3)) * 8)]; }

  // prologue: stage tiles 0..2 (3 loads/thread each: A, B0, B1)
  for (int tt = 0; tt < 3; ++tt) { STAGE_A(tt); STAGE_B(tt, 0); STAGE_B(tt, 1); }
  asm volatile("s_waitcnt vmcnt(6)" ::: "memory");  // tile 0 landed
  __builtin_amdgcn_s_barrier();

  for (int t = 0; t < nkt; ++t) {
    int cur = t & 3;
    bool pf = (t + 3 < nkt);
    // ---- phase 0 ----
    bf16x8 a[4], b0, b1, b2, b3;
    RD_A(cur, 0, a[0]); RD_A(cur, 1, a[1]); RD_A(cur, 2, a[2]); RD_A(cur, 3, a[3]);
    RD_B(cur, 0, b0); RD_B(cur, 1, b1);
    if (pf) { STAGE_A(t + 3); STAGE_B(t + 3, 0); }
    __builtin_amdgcn_s_barrier();
    __builtin_amdgcn_s_setprio(1);
    for (int fm = 0; fm < 4; ++fm) {
      acc[fm][0] = mfma16(a[fm], b0, acc[fm][0]);
      acc[fm][1] = mfma16(a[fm], b1, acc[fm][1]);
    }
    __builtin_amdgcn_s_setprio(0);
    __builtin_amdgcn_s_barrier();
    // ---- phase 1 ----
    RD_B(cur, 2, b2); RD_B(cur, 3, b3);
    if (pf) STAGE_B(t + 3, 1);
    asm volatile("s_waitcnt vmcnt(6)" ::: "memory");  // tile t+1 landed
    __builtin_amdgcn_s_barrier();
    __builtin_amdgcn_s_setprio(1);
    for (int fm = 0; fm < 4; ++fm) {
      acc[fm][2] = mfma16(a[fm], b2, acc[fm][2]);
      acc[fm][3] = mfma16(a[fm], b3, acc[fm][3]);
    }
    __builtin_amdgcn_s_setprio(0);
    __builtin_amdgcn_s_barrier();
  }
#undef STAGE_A
#undef STAGE_B
#undef RD_A
#undef RD_B

  for (int fm = 0; fm < 4; ++fm)
    for (int fn = 0; fn < 4; ++fn)
      for (int rr = 0; rr < 4; ++rr) {
        int row = row0 + wm * 64 + fm * 16 + hi * 4 + rr;  // C/D: row=(l>>4)*4+r
        int col = col0 + wn * 64 + fn * 16 + lo;           //      col=l&15
        store_out(&C[(size_t)row * N + col], acc[fm][fn][rr]);
      }
}

// ---------- RoPE in place on q,k regions of qkv ----------
__global__ __launch_bounds__(256) void rope_kernel(u16* __restrict__ qkv,
                                                   const float* __restrict__ cosb,
                                                   const float* __restrict__ sinb) {
  int idx = blockIdx.x * 256 + threadIdx.x;   // (m, head<40, d<64)
  int d = idx & 63;
  int head = (idx >> 6) % 40;
  int m = idx / (64 * 40);
  int s = m & (SEQ - 1);
  int col = head < 32 ? head * 128 : 4096 + (head - 32) * 128;
  u16* p = qkv + (size_t)m * NQKV + col;
  float x1 = bf2f(p[d]), x2 = bf2f(p[d + 64]);
  float c = cosb[s * 64 + d], sn = sinb[s * 64 + d];
  p[d] = f2bf(x1 * c - x2 * sn);
  p[d + 64] = f2bf(x2 * c + x1 * sn);
}

// ---------- V transpose: qkv v-region -> Vt[b][kvh][d][S] ----------
__global__ __launch_bounds__(256) void vtrans_kernel(const u16* __restrict__ qkv,
                                                     u16* __restrict__ Vt) {
  __shared__ u16 tile[32][33];
  int bid = blockIdx.x;
  int dt = bid & 3;
  int st = (bid >> 2) & 63;
  int bk = bid >> 8;               // b*8+kvh
  int b = bk >> 3, kvh = bk & 7;
  int tx = threadIdx.x & 31, ty = threadIdx.x >> 5;
  for (int i = 0; i < 4; ++i) {
    int s = st * 32 + ty + 8 * i;
    tile[ty + 8 * i][tx] = qkv[(size_t)(b * SEQ + s) * NQKV + 5120 + kvh * 128 + dt * 32 + tx];
  }
  __syncthreads();
  for (int i = 0; i < 4; ++i) {
    int d = dt * 32 + ty + 8 * i;
    Vt[((size_t)bk * 128 + d) * SEQ + st * 32 + tx] = tile[tx][ty + 8 * i];
  }
}

// ---------- flash attention: 4 waves/block, 32 q-rows/wave, KBLK=64 ----------
__global__ __launch_bounds__(256) void flash_kernel(const u16* __restrict__ qkv,
                                                    const u16* __restrict__ Vt,
                                                    u16* __restrict__ attn) {
  const float scale = 0.08838834764831843f;  // 1/sqrt(128)
  int bid = blockIdx.x;
  int bh = bid & 63;                // (b,h) fastest: heavy tiles spread over CUs
  int qc = 15 - (bid >> 6);         // heavy first
  int h = bh & 31;
  int b = bh >> 5;
  int w = threadIdx.x >> 6, l = threadIdx.x & 63;
  int lo = l & 15, hi = l >> 4;
  int q0 = qc * 128 + w * 32;
  int kvh = h >> 2;

  __shared__ __align__(16) u16 Ks[64 * 128];      // [row][chunk^=(row&7)] 16B chunks
  __shared__ __align__(16) u16 Vs[128 * 64];      // [d]  [chunk^=(d&7)]   16B chunks
  __shared__ __align__(16) u16 P_lds[4][32][72];  // per-wave P, padded rows
  u16(*P)[72] = P_lds[w];

  bf16x8 aq[2][4];
  for (int s2 = 0; s2 < 2; ++s2) {
    const u16* qr = qkv + (size_t)(b * SEQ + q0 + s2 * 16 + lo) * NQKV + h * 128 + hi * 8;
    for (int dk = 0; dk < 4; ++dk) aq[s2][dk] = *(const bf16x8*)(qr + dk * 32);
  }
  f32x4 o[2][8] = {};
  float mreg[2][4], lreg[2][4];
  for (int s2 = 0; s2 < 2; ++s2)
    for (int r = 0; r < 4; ++r) { mreg[s2][r] = -1e30f; lreg[s2][r] = 0.f; }

  const u16* kb = qkv + (size_t)(b * SEQ) * NQKV + 4096 + kvh * 128;
  const u16* vtb = Vt + (size_t)(b * 8 + kvh) * 128 * SEQ;
  int ktend = 2 * qc + 1;            // block-uniform k-loop
  int myktmax = 2 * qc + (w >> 1);   // this wave's causal limit

  for (int kt = 0; kt <= ktend; ++kt) {
    // ---- stage K tile: 64 rows x 256B; 16 wave-instrs, 4/wave ----
    for (int i = 0; i < 4; ++i) {
      int ck = w * 4 + i;
      int r = ck * 4 + (l >> 4);     // 4 rows per 1KB chunk, 16 lanes/row
      int c = l & 15;                // 16B chunk within row
      gload16(kb + (size_t)(kt * 64 + r) * NQKV + (size_t)((c ^ (r & 7)) * 8),
              &Ks[ck * 512]);
    }
    // ---- stage Vt tile: 128 rows x 128B; 16 wave-instrs, 4/wave ----
    for (int i = 0; i < 4; ++i) {
      int ck = w * 4 + i;
      int r = ck * 8 + (l >> 3);     // 8 rows per 1KB chunk, 8 lanes/row
      int c = l & 7;
      gload16(vtb + (size_t)r * SEQ + kt * 64 + ((c ^ (r & 7)) * 8),
              &Vs[ck * 512]);
    }
    __syncthreads();                 // drains vmcnt, tiles ready

    bool active = (kt <= myktmax);
    if (active) {
      // ---- scores: S = Q K^T (K from swizzled LDS) ----
      f32x4 sc[2][4];
      for (int ct = 0; ct < 4; ++ct) {
        bf16x8 kf[4];
        int row = ct * 16 + lo;
        for (int dk = 0; dk < 4; ++dk)
          kf[dk] = *(const bf16x8*)&Ks[row * 128 + (((dk * 4 + hi) ^ (row & 7)) * 8)];
        for (int s2 = 0; s2 < 2; ++s2) {
          f32x4 a = {0.f, 0.f, 0.f, 0.f};
          for (int dk = 0; dk < 4; ++dk) a = mfma16(aq[s2][dk], kf[dk], a);
          sc[s2][ct] = a;
        }
      }
      bool masked = (kt == myktmax);
      // ---- online softmax ----
      for (int s2 = 0; s2 < 2; ++s2) {
        float pv[4][4];
        float tm[4] = {-1e30f, -1e30f, -1e30f, -1e30f};
        for (int ct = 0; ct < 4; ++ct)
          for (int r = 0; r < 4; ++r) {
            float v = sc[s2][ct][r] * scale;
            if (masked && (kt * 64 + ct * 16 + lo > q0 + s2 * 16 + hi * 4 + r)) v = -1e30f;
            pv[ct][r] = v;
            tm[r] = fmaxf(tm[r], v);
          }
        for (int r = 0; r < 4; ++r) {
          float t = tm[r];
          t = fmaxf(t, __shfl_xor(t, 1));
          t = fmaxf(t, __shfl_xor(t, 2));
          t = fmaxf(t, __shfl_xor(t, 4));
          t = fmaxf(t, __shfl_xor(t, 8));
          float mnew = fmaxf(mreg[s2][r], t);
          float alpha = __expf(mreg[s2][r] - mnew);
          mreg[s2][r] = mnew;
          float rs = 0.f;
          for (int ct = 0; ct < 4; ++ct) {
            float p = __expf(pv[ct][r] - mnew);
            pv[ct][r] = p;
            rs += p;
          }
          rs += __shfl_xor(rs, 1);
          rs += __shfl_xor(rs, 2);
          rs += __shfl_xor(rs, 4);
          rs += __shfl_xor(rs, 8);
          lreg[s2][r] = lreg[s2][r] * alpha + rs;
          for (int dt = 0; dt < 8; ++dt) o[s2][dt][r] *= alpha;
          for (int ct = 0; ct < 4; ++ct)
            P[s2 * 16 + hi * 4 + r][ct * 16 + lo] = f2bf(pv[ct][r]);
        }
      }
      asm volatile("s_waitcnt lgkmcnt(0)" ::: "memory");  // P visible (per-wave)
      // ---- O += P V (V from swizzled LDS) ----
      for (int kk = 0; kk < 2; ++kk) {
        bf16x8 ap[2];
        for (int s2 = 0; s2 < 2; ++s2)
          ap[s2] = *(const bf16x8*)&P[s2 * 16 + lo][kk * 32 + hi * 8];
        for (int dt = 0; dt < 8; ++dt) {
          int row = dt * 16 + lo;
          bf16x8 vf = *(const bf16x8*)&Vs[row * 64 + (((kk * 4 + hi) ^ (row & 7)) * 8)];
          for (int s2 = 0; s2 < 2; ++s2) o[s2][dt] = mfma16(ap[s2], vf, o[s2][dt]);
        }
      }
    }
    __syncthreads();                 // all waves done before next stage
  }
  // ---- epilogue ----
  for (int s2 = 0; s2 < 2; ++s2)
    for (int dt = 0; dt < 8; ++dt)
      for (int r = 0; r < 4; ++r) {
        float v2 = o[s2][dt][r] / lreg[s2][r];
        attn[(size_t)(b * SEQ + q0 + s2 * 16 + hi * 4 + r) * 4096 + h * 128 + dt * 16 + lo] = f2bf(v2);
      }
}

extern "C" void kernel_launch(void* const* d_in, const int* in_sizes, int n_in,
                              void* d_out, int out_size, void* d_ws, size_t ws_size,
                              hipStream_t stream) {
  const float* hidden = (const float*)d_in[0];
  const float* Wqkv = (const float*)d_in[1];
  const float* Wo = (const float*)d_in[2];
  const float* cosb = (const float*)d_in[3];
  const float* sinb = (const float*)d_in[4];
  // d_in[5] (attention_mask) is exactly causal triu(-1e9): applied analytically.
  float* out = (float*)d_out;

  char* ws = (char*)d_ws;
  u16* R1 = (u16*)ws;                  // 50,331,648 B : Wqkv_t, then attn
  u16* R2 = (u16*)(ws + 50331648);     // 50,331,648 B : qkv, then Wo_t
  u16* R3 = (u16*)(ws + 100663296);    // 33,554,432 B : hidden_bf16, then Vt
  // total 128 MiB

  // 1. hidden fp32 -> bf16
  conv_kernel<<<16384, 256, 0, stream>>>(hidden, R3);
  // 2. Wqkv [4096][6144] -> [6144][4096] bf16
  transconv_kernel<<<dim3(6144 / 32, 4096 / 32), 256, 0, stream>>>(Wqkv, R1, 4096, 6144);
  // 3. qkv = hidden x Wqkv  (bf16 out); grid 768 = (6144/256)*(4096/128)
  gemm_kernel<u16><<<768, 512, 0, stream>>>(R3, R1, R2, 4096, 6144, 4096, 32);
  // 4. RoPE on q,k
  rope_kernel<<<40960, 256, 0, stream>>>(R2, cosb, sinb);
  // 5. V -> Vt[b][kvh][d][S]
  vtrans_kernel<<<4096, 256, 0, stream>>>(R2, R3);
  // 6. flash attention -> attn (bf16)
  flash_kernel<<<1024, 256, 0, stream>>>(R2, R3, R1);
  // 7. Wo [4096][4096] -> [4096][4096]^T bf16
  transconv_kernel<<<dim3(4096 / 32, 4096 / 32), 256, 0, stream>>>(Wo, R2, 4096, 4096);
  // 8. out = attn x Wo (fp32 out); grid 512 = (4096/256)*(4096/128)
  gemm_kernel<float><<<512, 512, 0, stream>>>(R1, R2, out, 4096, 4096, 4096, 32);
}

// Round 5
// 684.790 us; speedup vs baseline: 1.9912x; 1.1351x over previous
//
#include <hip/hip_runtime.h>

typedef unsigned short u16;
typedef __bf16 bf16x8 __attribute__((ext_vector_type(8)));
typedef float f32x4 __attribute__((ext_vector_type(4)));
typedef u16 u16x4 __attribute__((ext_vector_type(4)));

#define SEQ 2048
#define NQKV 6144
#define HID 4096

__device__ inline u16 f2bf(float f) {
  union { float f; unsigned u; } x; x.f = f;
  unsigned r = x.u + 0x7fffu + ((x.u >> 16) & 1u);  // RNE
  return (u16)(r >> 16);
}
__device__ inline float bf2f(u16 u) {
  union { unsigned u; float f; } x; x.u = ((unsigned)u) << 16;
  return x.f;
}
__device__ inline f32x4 mfma16(bf16x8 a, bf16x8 b, f32x4 c) {
  return __builtin_amdgcn_mfma_f32_16x16x32_bf16(a, b, c, 0, 0, 0);
}
__device__ inline void gload16(const void* g, void* l) {
  __builtin_amdgcn_global_load_lds((const __attribute__((address_space(1))) void*)g,
                                   (__attribute__((address_space(3))) void*)l,
                                   16, 0, 0);
}

// ---------- fp32 -> bf16 contiguous convert ----------
__global__ __launch_bounds__(256) void conv_kernel(const float* __restrict__ in,
                                                   u16* __restrict__ out) {
  int i = (blockIdx.x * 256 + threadIdx.x) * 4;
  float4 v = *(const float4*)(in + i);
  u16x4 o;
  o[0] = f2bf(v.x); o[1] = f2bf(v.y); o[2] = f2bf(v.z); o[3] = f2bf(v.w);
  *(u16x4*)(out + i) = o;
}

// ---------- fp32 [R][C] -> bf16 [C][R] transpose-convert ----------
__global__ __launch_bounds__(256) void transconv_kernel(const float* __restrict__ in,
                                                        u16* __restrict__ out,
                                                        int R, int C) {
  __shared__ u16 tile[32][33];
  int c0 = blockIdx.x * 32, r0 = blockIdx.y * 32;
  int tx = threadIdx.x & 31, ty = threadIdx.x >> 5;
  for (int i = 0; i < 4; ++i)
    tile[ty + 8 * i][tx] = f2bf(in[(size_t)(r0 + ty + 8 * i) * C + c0 + tx]);
  __syncthreads();
  for (int i = 0; i < 4; ++i)
    out[(size_t)(c0 + ty + 8 * i) * R + r0 + tx] = tile[tx][ty + 8 * i];
}

// ---------- bf16 GEMM: A[M][K] x Bt[N][K] -> C[M][N] ----------
// R4 post-mortem: 128x256/BK32 hit an L2-miss wall (FETCH 418MB, 1.5TB/s miss
// traffic; MfmaUtil stuck 31%). This round: guide's proven 256x256 geometry
// (m198/m201): BK=64, 8 waves 2Mx4N, wave tile 128x64 (32 acc frags -> 5.3
// MFMA per ds_read), LDS 2x64KB dbuf, 4 phases/K-tile x 16 MFMA with A/B
// fragment reuse across quadrant phases, stage 8 gloads/thread spread over
// phases 0-2, one vmcnt(0)+barrier per tile boundary. Swizzle: 16B chunk
// c ^= row&7 on 128B rows (uniform bank-quad coverage; measured 0-conflict
// construction in R4), pre-swizzled global source + linear LDS dest (m173).
// Dbuf-2 safety: tile t+1 loads (issued during tile t) write buf^1 whose
// readers (tile t-1) finished before tile t's entry barrier.
__device__ inline void store_out(u16* p, float v) { *p = f2bf(v); }
__device__ inline void store_out(float* p, float v) { *p = v; }

template <typename OutT>
__global__ __launch_bounds__(512, 2) void gemm_kernel(const u16* __restrict__ A,
                                                      const u16* __restrict__ Bt,
                                                      OutT* __restrict__ C,
                                                      int M, int N, int K, int nby) {
  __shared__ __align__(16) u16 As[2][256 * 64];
  __shared__ __align__(16) u16 Bs[2][256 * 64];
  int nwg = gridDim.x;                      // multiple of 8
  int bid = blockIdx.x;
  int s = (bid & 7) * (nwg >> 3) + (bid >> 3);   // XCD-contiguous, bijective
  int by = s % nby, bx = s / nby;
  int row0 = by * 256, col0 = bx * 256;
  int tid = threadIdx.x, w = tid >> 6, l = tid & 63;
  int wm = w >> 2, wn = w & 3;              // wave tile 128x64
  int lo = l & 15, hi = l >> 4;
  int lr = l >> 3;                          // staging: row within 8-row chunk
  int lc = (l & 7) ^ ((l >> 3) & 7);        // pre-swizzled source k-chunk
  const u16* Ab = A + (size_t)row0 * K;
  const u16* Bb = Bt + (size_t)col0 * K;
  int nkt = K >> 6;

  f32x4 acc[8][4] = {};

  // stage group g (0..3): chunk ci = g*8+w covers rows ci*8..ci*8+7 (1KB)
#define STAGE(tt, g)                                                          \
  { int ci = (g) * 8 + w;                                                     \
    gload16(Ab + (size_t)(ci * 8 + lr) * K + (tt) * 64 + lc * 8,              \
            &As[(tt) & 1][ci * 512]);                                         \
    gload16(Bb + (size_t)(ci * 8 + lr) * K + (tt) * 64 + lc * 8,              \
            &Bs[(tt) & 1][ci * 512]); }
#define RD_A(cur, qm, fm, kh, dst)                                            \
  { int r = wm * 128 + (qm) * 64 + (fm) * 16 + lo;                            \
    dst = *(const bf16x8*)&As[cur][r * 64 + ((((kh) * 4 + hi) ^ (r & 7)) * 8)]; }
#define RD_B(cur, qn, fn, kh, dst)                                            \
  { int r = wn * 64 + (qn) * 32 + (fn) * 16 + lo;                             \
    dst = *(const bf16x8*)&Bs[cur][r * 64 + ((((kh) * 4 + hi) ^ (r & 7)) * 8)]; }

  // prologue: stage tile 0 fully
  STAGE(0, 0); STAGE(0, 1); STAGE(0, 2); STAGE(0, 3);
  asm volatile("s_waitcnt vmcnt(0)" ::: "memory");
  __builtin_amdgcn_s_barrier();

  bf16x8 af[4][2], bfr[2][2];
  for (int t = 0; t < nkt; ++t) {
    int cur = t & 1;
    bool pf = (t + 1 < nkt);
    // ---- phase 0: quadrant (qm=0, qn=0); load A0, B0 ----
    for (int fm = 0; fm < 4; ++fm)
      for (int kh = 0; kh < 2; ++kh) RD_A(cur, 0, fm, kh, af[fm][kh]);
    for (int fn = 0; fn < 2; ++fn)
      for (int kh = 0; kh < 2; ++kh) RD_B(cur, 0, fn, kh, bfr[fn][kh]);
    if (pf) { STAGE(t + 1, 0); STAGE(t + 1, 1); }
    __builtin_amdgcn_s_barrier();
    __builtin_amdgcn_s_setprio(1);
    for (int fm = 0; fm < 4; ++fm)
      for (int fn = 0; fn < 2; ++fn)
        for (int kh = 0; kh < 2; ++kh)
          acc[fm][fn] = mfma16(af[fm][kh], bfr[fn][kh], acc[fm][fn]);
    __builtin_amdgcn_s_setprio(0);
    // ---- phase 1: quadrant (1,0); new A1, reuse B0 ----
    for (int fm = 0; fm < 4; ++fm)
      for (int kh = 0; kh < 2; ++kh) RD_A(cur, 1, fm, kh, af[fm][kh]);
    if (pf) STAGE(t + 1, 2);
    __builtin_amdgcn_s_barrier();
    __builtin_amdgcn_s_setprio(1);
    for (int fm = 0; fm < 4; ++fm)
      for (int fn = 0; fn < 2; ++fn)
        for (int kh = 0; kh < 2; ++kh)
          acc[4 + fm][fn] = mfma16(af[fm][kh], bfr[fn][kh], acc[4 + fm][fn]);
    __builtin_amdgcn_s_setprio(0);
    // ---- phase 2: quadrant (1,1); new B1, reuse A1 ----
    for (int fn = 0; fn < 2; ++fn)
      for (int kh = 0; kh < 2; ++kh) RD_B(cur, 1, fn, kh, bfr[fn][kh]);
    if (pf) STAGE(t + 1, 3);
    __builtin_amdgcn_s_barrier();
    __builtin_amdgcn_s_setprio(1);
    for (int fm = 0; fm < 4; ++fm)
      for (int fn = 0; fn < 2; ++fn)
        for (int kh = 0; kh < 2; ++kh)
          acc[4 + fm][2 + fn] = mfma16(af[fm][kh], bfr[fn][kh], acc[4 + fm][2 + fn]);
    __builtin_amdgcn_s_setprio(0);
    // ---- phase 3: quadrant (0,1); re-read A0, reuse B1 ----
    for (int fm = 0; fm < 4; ++fm)
      for (int kh = 0; kh < 2; ++kh) RD_A(cur, 0, fm, kh, af[fm][kh]);
    __builtin_amdgcn_s_barrier();
    __builtin_amdgcn_s_setprio(1);
    for (int fm = 0; fm < 4; ++fm)
      for (int fn = 0; fn < 2; ++fn)
        for (int kh = 0; kh < 2; ++kh)
          acc[fm][2 + fn] = mfma16(af[fm][kh], bfr[fn][kh], acc[fm][2 + fn]);
    __builtin_amdgcn_s_setprio(0);
    // ---- tile boundary: next tile's LDS must be landed ----
    asm volatile("s_waitcnt vmcnt(0)" ::: "memory");
    __builtin_amdgcn_s_barrier();
  }
#undef STAGE
#undef RD_A
#undef RD_B

  for (int im = 0; im < 8; ++im)
    for (int in = 0; in < 4; ++in)
      for (int rr = 0; rr < 4; ++rr) {
        int row = row0 + wm * 128 + im * 16 + hi * 4 + rr;  // C/D: row=(l>>4)*4+r
        int col = col0 + wn * 64 + in * 16 + lo;            //      col=l&15
        store_out(&C[(size_t)row * N + col], acc[im][in][rr]);
      }
}

// ---------- RoPE in place on q,k regions of qkv ----------
__global__ __launch_bounds__(256) void rope_kernel(u16* __restrict__ qkv,
                                                   const float* __restrict__ cosb,
                                                   const float* __restrict__ sinb) {
  int idx = blockIdx.x * 256 + threadIdx.x;   // (m, head<40, d<64)
  int d = idx & 63;
  int head = (idx >> 6) % 40;
  int m = idx / (64 * 40);
  int s = m & (SEQ - 1);
  int col = head < 32 ? head * 128 : 4096 + (head - 32) * 128;
  u16* p = qkv + (size_t)m * NQKV + col;
  float x1 = bf2f(p[d]), x2 = bf2f(p[d + 64]);
  float c = cosb[s * 64 + d], sn = sinb[s * 64 + d];
  p[d] = f2bf(x1 * c - x2 * sn);
  p[d + 64] = f2bf(x2 * c + x1 * sn);
}

// ---------- V transpose: qkv v-region -> Vt[b][kvh][d][S] ----------
__global__ __launch_bounds__(256) void vtrans_kernel(const u16* __restrict__ qkv,
                                                     u16* __restrict__ Vt) {
  __shared__ u16 tile[32][33];
  int bid = blockIdx.x;
  int dt = bid & 3;
  int st = (bid >> 2) & 63;
  int bk = bid >> 8;               // b*8+kvh
  int b = bk >> 3, kvh = bk & 7;
  int tx = threadIdx.x & 31, ty = threadIdx.x >> 5;
  for (int i = 0; i < 4; ++i) {
    int s = st * 32 + ty + 8 * i;
    tile[ty + 8 * i][tx] = qkv[(size_t)(b * SEQ + s) * NQKV + 5120 + kvh * 128 + dt * 32 + tx];
  }
  __syncthreads();
  for (int i = 0; i < 4; ++i) {
    int d = dt * 32 + ty + 8 * i;
    Vt[((size_t)bk * 128 + d) * SEQ + st * 32 + tx] = tile[tx][ty + 8 * i];
  }
}

// ---------- flash attention: 4 waves/block, 32 q-rows/wave, KBLK=64 ----------
__global__ __launch_bounds__(256) void flash_kernel(const u16* __restrict__ qkv,
                                                    const u16* __restrict__ Vt,
                                                    u16* __restrict__ attn) {
  const float scale = 0.08838834764831843f;  // 1/sqrt(128)
  int bid = blockIdx.x;
  int bh = bid & 63;                // (b,h) fastest: heavy tiles spread over CUs
  int qc = 15 - (bid >> 6);         // heavy first
  int h = bh & 31;
  int b = bh >> 5;
  int w = threadIdx.x >> 6, l = threadIdx.x & 63;
  int lo = l & 15, hi = l >> 4;
  int q0 = qc * 128 + w * 32;
  int kvh = h >> 2;

  __shared__ __align__(16) u16 Ks[64 * 128];      // [row][chunk^=(row&7)] 16B chunks
  __shared__ __align__(16) u16 Vs[128 * 64];      // [d]  [chunk^=(d&7)]   16B chunks
  __shared__ __align__(16) u16 P_lds[4][32][72];  // per-wave P, padded rows
  u16(*P)[72] = P_lds[w];

  bf16x8 aq[2][4];
  for (int s2 = 0; s2 < 2; ++s2) {
    const u16* qr = qkv + (size_t)(b * SEQ + q0 + s2 * 16 + lo) * NQKV + h * 128 + hi * 8;
    for (int dk = 0; dk < 4; ++dk) aq[s2][dk] = *(const bf16x8*)(qr + dk * 32);
  }
  f32x4 o[2][8] = {};
  float mreg[2][4], lreg[2][4];
  for (int s2 = 0; s2 < 2; ++s2)
    for (int r = 0; r < 4; ++r) { mreg[s2][r] = -1e30f; lreg[s2][r] = 0.f; }

  const u16* kb = qkv + (size_t)(b * SEQ) * NQKV + 4096 + kvh * 128;
  const u16* vtb = Vt + (size_t)(b * 8 + kvh) * 128 * SEQ;
  int ktend = 2 * qc + 1;            // block-uniform k-loop
  int myktmax = 2 * qc + (w >> 1);   // this wave's causal limit

  for (int kt = 0; kt <= ktend; ++kt) {
    // ---- stage K tile: 64 rows x 256B; 16 wave-instrs, 4/wave ----
    for (int i = 0; i < 4; ++i) {
      int ck = w * 4 + i;
      int r = ck * 4 + (l >> 4);     // 4 rows per 1KB chunk, 16 lanes/row
      int c = l & 15;                // 16B chunk within row
      gload16(kb + (size_t)(kt * 64 + r) * NQKV + (size_t)((c ^ (r & 7)) * 8),
              &Ks[ck * 512]);
    }
    // ---- stage Vt tile: 128 rows x 128B; 16 wave-instrs, 4/wave ----
    for (int i = 0; i < 4; ++i) {
      int ck = w * 4 + i;
      int r = ck * 8 + (l >> 3);     // 8 rows per 1KB chunk, 8 lanes/row
      int c = l & 7;
      gload16(vtb + (size_t)r * SEQ + kt * 64 + ((c ^ (r & 7)) * 8),
              &Vs[ck * 512]);
    }
    __syncthreads();                 // drains vmcnt, tiles ready

    bool active = (kt <= myktmax);
    if (active) {
      // ---- scores: S = Q K^T (K from swizzled LDS) ----
      f32x4 sc[2][4];
      for (int ct = 0; ct < 4; ++ct) {
        bf16x8 kf[4];
        int row = ct * 16 + lo;
        for (int dk = 0; dk < 4; ++dk)
          kf[dk] = *(const bf16x8*)&Ks[row * 128 + (((dk * 4 + hi) ^ (row & 7)) * 8)];
        for (int s2 = 0; s2 < 2; ++s2) {
          f32x4 a = {0.f, 0.f, 0.f, 0.f};
          for (int dk = 0; dk < 4; ++dk) a = mfma16(aq[s2][dk], kf[dk], a);
          sc[s2][ct] = a;
        }
      }
      bool masked = (kt == myktmax);
      // ---- online softmax ----
      for (int s2 = 0; s2 < 2; ++s2) {
        float pv[4][4];
        float tm[4] = {-1e30f, -1e30f, -1e30f, -1e30f};
        for (int ct = 0; ct < 4; ++ct)
          for (int r = 0; r < 4; ++r) {
            float v = sc[s2][ct][r] * scale;
            if (masked && (kt * 64 + ct * 16 + lo > q0 + s2 * 16 + hi * 4 + r)) v = -1e30f;
            pv[ct][r] = v;
            tm[r] = fmaxf(tm[r], v);
          }
        for (int r = 0; r < 4; ++r) {
          float t = tm[r];
          t = fmaxf(t, __shfl_xor(t, 1));
          t = fmaxf(t, __shfl_xor(t, 2));
          t = fmaxf(t, __shfl_xor(t, 4));
          t = fmaxf(t, __shfl_xor(t, 8));
          float mnew = fmaxf(mreg[s2][r], t);
          float alpha = __expf(mreg[s2][r] - mnew);
          mreg[s2][r] = mnew;
          float rs = 0.f;
          for (int ct = 0; ct < 4; ++ct) {
            float p = __expf(pv[ct][r] - mnew);
            pv[ct][r] = p;
            rs += p;
          }
          rs += __shfl_xor(rs, 1);
          rs += __shfl_xor(rs, 2);
          rs += __shfl_xor(rs, 4);
          rs += __shfl_xor(rs, 8);
          lreg[s2][r] = lreg[s2][r] * alpha + rs;
          for (int dt = 0; dt < 8; ++dt) o[s2][dt][r] *= alpha;
          for (int ct = 0; ct < 4; ++ct)
            P[s2 * 16 + hi * 4 + r][ct * 16 + lo] = f2bf(pv[ct][r]);
        }
      }
      asm volatile("s_waitcnt lgkmcnt(0)" ::: "memory");  // P visible (per-wave)
      // ---- O += P V (V from swizzled LDS) ----
      for (int kk = 0; kk < 2; ++kk) {
        bf16x8 ap[2];
        for (int s2 = 0; s2 < 2; ++s2)
          ap[s2] = *(const bf16x8*)&P[s2 * 16 + lo][kk * 32 + hi * 8];
        for (int dt = 0; dt < 8; ++dt) {
          int row = dt * 16 + lo;
          bf16x8 vf = *(const bf16x8*)&Vs[row * 64 + (((kk * 4 + hi) ^ (row & 7)) * 8)];
          for (int s2 = 0; s2 < 2; ++s2) o[s2][dt] = mfma16(ap[s2], vf, o[s2][dt]);
        }
      }
    }
    __syncthreads();                 // all waves done before next stage
  }
  // ---- epilogue ----
  for (int s2 = 0; s2 < 2; ++s2)
    for (int dt = 0; dt < 8; ++dt)
      for (int r = 0; r < 4; ++r) {
        float v2 = o[s2][dt][r] / lreg[s2][r];
        attn[(size_t)(b * SEQ + q0 + s2 * 16 + hi * 4 + r) * 4096 + h * 128 + dt * 16 + lo] = f2bf(v2);
      }
}

extern "C" void kernel_launch(void* const* d_in, const int* in_sizes, int n_in,
                              void* d_out, int out_size, void* d_ws, size_t ws_size,
                              hipStream_t stream) {
  const float* hidden = (const float*)d_in[0];
  const float* Wqkv = (const float*)d_in[1];
  const float* Wo = (const float*)d_in[2];
  const float* cosb = (const float*)d_in[3];
  const float* sinb = (const float*)d_in[4];
  // d_in[5] (attention_mask) is exactly causal triu(-1e9): applied analytically.
  float* out = (float*)d_out;

  char* ws = (char*)d_ws;
  u16* R1 = (u16*)ws;                  // 50,331,648 B : Wqkv_t, then attn
  u16* R2 = (u16*)(ws + 50331648);     // 50,331,648 B : qkv, then Wo_t
  u16* R3 = (u16*)(ws + 100663296);    // 33,554,432 B : hidden_bf16, then Vt
  // total 128 MiB

  // 1. hidden fp32 -> bf16
  conv_kernel<<<16384, 256, 0, stream>>>(hidden, R3);
  // 2. Wqkv [4096][6144] -> [6144][4096] bf16
  transconv_kernel<<<dim3(6144 / 32, 4096 / 32), 256, 0, stream>>>(Wqkv, R1, 4096, 6144);
  // 3. qkv = hidden x Wqkv (bf16 out); grid 384 = (4096/256)*(6144/256)
  gemm_kernel<u16><<<384, 512, 0, stream>>>(R3, R1, R2, 4096, 6144, 4096, 16);
  // 4. RoPE on q,k
  rope_kernel<<<40960, 256, 0, stream>>>(R2, cosb, sinb);
  // 5. V -> Vt[b][kvh][d][S]
  vtrans_kernel<<<4096, 256, 0, stream>>>(R2, R3);
  // 6. flash attention -> attn (bf16)
  flash_kernel<<<1024, 256, 0, stream>>>(R2, R3, R1);
  // 7. Wo [4096][4096] -> [4096][4096]^T bf16
  transconv_kernel<<<dim3(4096 / 32, 4096 / 32), 256, 0, stream>>>(Wo, R2, 4096, 4096);
  // 8. out = attn x Wo (fp32 out); grid 256 = (4096/256)*(4096/256)
  gemm_kernel<float><<<256, 512, 0, stream>>>(R1, R2, out, 4096, 4096, 4096, 16);
}